// Round 1
// baseline (423.523 us; speedup 1.0000x reference)
//
#include <hip/hip_runtime.h>
#include <math.h>

#define B_  512
#define I_  8
#define C_  1152
#define J_  10
#define S_  16
#define K1  (I_ * C_)   // 9216
#define M2  (J_ * S_)   // 160

// ---------------------------------------------------------------------------
// Transpose x [B][K1] -> xT [K1][B]   (k = i*1152 + c is x's natural flat idx)
__global__ __launch_bounds__(256) void k_transpose(const float* __restrict__ x,
                                                   float* __restrict__ xT) {
    __shared__ float tile[32][33];
    const int k0 = blockIdx.x * 32;
    const int b0 = blockIdx.y * 32;
    const int tx = threadIdx.x;   // 0..31
    const int ty = threadIdx.y;   // 0..7
    #pragma unroll
    for (int r = 0; r < 32; r += 8)
        tile[ty + r][tx] = x[(size_t)(b0 + ty + r) * K1 + k0 + tx];
    __syncthreads();
    #pragma unroll
    for (int r = 0; r < 32; r += 8)
        xT[(size_t)(k0 + ty + r) * B_ + b0 + tx] = tile[tx][ty + r];
}

// ---------------------------------------------------------------------------
__global__ __launch_bounds__(256) void k_zero(float* __restrict__ p, int n) {
    int t = blockIdx.x * 256 + threadIdx.x;
    if (t < n) p[t] = 0.0f;
}

// ---------------------------------------------------------------------------
// softmax over J per input capsule c
__global__ __launch_bounds__(256) void k_softmax(const float* __restrict__ b_ij,
                                                 float* __restrict__ cnorm) {
    int c = blockIdx.x * 256 + threadIdx.x;
    if (c >= C_) return;
    float v[J_];
    float mx = -1e30f;
    #pragma unroll
    for (int j = 0; j < J_; j++) { v[j] = b_ij[c * J_ + j]; mx = fmaxf(mx, v[j]); }
    float sum = 0.0f;
    #pragma unroll
    for (int j = 0; j < J_; j++) { v[j] = expf(v[j] - mx); sum += v[j]; }
    float inv = 1.0f / sum;
    #pragma unroll
    for (int j = 0; j < J_; j++) cnorm[c * J_ + j] = v[j] * inv;
}

// ---------------------------------------------------------------------------
// Af[j][k=(i*1152+c)][s'] = cnorm[c][j] * W[c][j][s'][i]
// thread index t == flat W index (coalesced W read)
__global__ __launch_bounds__(256) void k_fold(const float* __restrict__ W,
                                              const float* __restrict__ cnorm,
                                              float* __restrict__ Af) {
    int t = blockIdx.x * 256 + threadIdx.x;
    if (t >= C_ * J_ * S_ * I_) return;
    int i = t & 7;
    int s = (t >> 3) & 15;
    int r = t >> 7;          // c*10 + j
    int j = r % 10;
    int c = r / 10;
    Af[((size_t)j * K1 + i * C_ + c) * S_ + s] = cnorm[c * J_ + j] * W[t];
}

// ---------------------------------------------------------------------------
// s[j][b][s'] += sum_k Af[j][k][s'] * xT[k][b]
// grid (4 n-tiles of 128, 10 j, 8 k-splits), block 256
__global__ __launch_bounds__(256) void k_sgemm(const float* __restrict__ Af,
                                               const float* __restrict__ xT,
                                               float* __restrict__ s_buf) {
    __shared__ float As[32][16];   // flat == Af chunk layout
    __shared__ float Bs[32][128];
    const int j    = blockIdx.y;
    const int n0   = blockIdx.x * 128;
    const int kbeg = blockIdx.z * 1152;
    const int t    = threadIdx.x;
    const int nl   = (t & 31) * 4;
    const int m0   = (t >> 5) * 2;
    float acc[2][4] = {};
    const float* Afj = Af + (size_t)j * K1 * S_;
    for (int kk = kbeg; kk < kbeg + 1152; kk += 32) {
        // As: 512 contiguous floats (Af rows are [k][16])
        ((float2*)As)[t] = ((const float2*)(Afj + (size_t)kk * S_))[t];
        // Bs: 32 rows of 128 from xT
        {
            int krow = t >> 3;
            int cc   = (t & 7) * 16;
            const float4* src = (const float4*)(xT + (size_t)(kk + krow) * B_ + n0 + cc);
            float4* dst = (float4*)&Bs[krow][cc];
            #pragma unroll
            for (int e = 0; e < 4; e++) dst[e] = src[e];
        }
        __syncthreads();
        #pragma unroll
        for (int k = 0; k < 32; k++) {
            float a0 = As[k][m0], a1 = As[k][m0 + 1];
            float4 b = *(const float4*)&Bs[k][nl];
            acc[0][0] += a0 * b.x; acc[0][1] += a0 * b.y;
            acc[0][2] += a0 * b.z; acc[0][3] += a0 * b.w;
            acc[1][0] += a1 * b.x; acc[1][1] += a1 * b.y;
            acc[1][2] += a1 * b.z; acc[1][3] += a1 * b.w;
        }
        __syncthreads();
    }
    #pragma unroll
    for (int e = 0; e < 2; e++)
        #pragma unroll
        for (int q = 0; q < 4; q++)
            atomicAdd(&s_buf[((size_t)j * B_ + (n0 + nl + q)) * S_ + m0 + e], acc[e][q]);
}

// ---------------------------------------------------------------------------
// squash per (j,b); write vT[(j*16+s')][b] and out[b][j][s']
__global__ __launch_bounds__(256) void k_squash(const float* __restrict__ s_buf,
                                                float* __restrict__ vT,
                                                float* __restrict__ out) {
    int t = blockIdx.x * 256 + threadIdx.x;
    if (t >= J_ * B_) return;
    int j = t / B_;
    int b = t % B_;
    const float* sp = s_buf + ((size_t)j * B_ + b) * S_;
    float sv[S_];
    float msq = 0.0f;
    #pragma unroll
    for (int e = 0; e < S_; e++) { sv[e] = sp[e]; msq += sv[e] * sv[e]; }
    float scale = msq / ((1.0f + msq) * sqrtf(msq));
    #pragma unroll
    for (int e = 0; e < S_; e++) {
        float v = sv[e] * scale;
        vT[(size_t)(j * S_ + e) * B_ + b] = v;
        out[((size_t)b * J_ + j) * S_ + e] = v;
    }
}

// ---------------------------------------------------------------------------
// T[m=(j*16+s')][n=(i*1152+c)] = sum_b vT[m][b] * x[b][n]   (M=160,N=9216,K=512)
// grid (72 n-tiles of 128, 10 m-tiles of 16), block 256
__global__ __launch_bounds__(256) void k_tgemm(const float* __restrict__ vT,
                                               const float* __restrict__ x,
                                               float* __restrict__ Tb) {
    __shared__ float As[32][17];   // padded: transposed store
    __shared__ float Bs[32][128];
    const int mb = blockIdx.y * 16;
    const int n0 = blockIdx.x * 128;
    const int t  = threadIdx.x;
    const int nl  = (t & 31) * 4;
    const int mm0 = (t >> 5) * 2;
    float acc[2][4] = {};
    for (int k0 = 0; k0 < B_; k0 += 32) {
        // As[k][m] = vT[(mb+m)*512 + k0 + k]; coalesced float2 along k
        {
            int f2 = t * 2;
            int m  = f2 >> 5;
            int k  = f2 & 31;
            float2 av = *(const float2*)&vT[(size_t)(mb + m) * B_ + k0 + k];
            As[k][m]     = av.x;
            As[k + 1][m] = av.y;
        }
        // Bs rows from x (natural layout [b][i*1152+c])
        {
            int krow = t >> 3;
            int cc   = (t & 7) * 16;
            const float4* src = (const float4*)(x + (size_t)(k0 + krow) * K1 + n0 + cc);
            float4* dst = (float4*)&Bs[krow][cc];
            #pragma unroll
            for (int e = 0; e < 4; e++) dst[e] = src[e];
        }
        __syncthreads();
        #pragma unroll
        for (int k = 0; k < 32; k++) {
            float a0 = As[k][mm0], a1 = As[k][mm0 + 1];
            float4 b = *(const float4*)&Bs[k][nl];
            acc[0][0] += a0 * b.x; acc[0][1] += a0 * b.y;
            acc[0][2] += a0 * b.z; acc[0][3] += a0 * b.w;
            acc[1][0] += a1 * b.x; acc[1][1] += a1 * b.y;
            acc[1][2] += a1 * b.z; acc[1][3] += a1 * b.w;
        }
        __syncthreads();
    }
    #pragma unroll
    for (int e = 0; e < 2; e++) {
        float4 o = make_float4(acc[e][0], acc[e][1], acc[e][2], acc[e][3]);
        *(float4*)&Tb[(size_t)(mb + mm0 + e) * K1 + n0 + nl] = o;
    }
}

// ---------------------------------------------------------------------------
// b_ij[c][j] += (1/B) * sum_{s,i} W[c][j][s][i] * T[(j*16+s)][i*1152+c]
// c is the fast thread index -> T reads coalesced
__global__ __launch_bounds__(256) void k_bupdate(const float* __restrict__ W,
                                                 const float* __restrict__ Tb,
                                                 float* __restrict__ b_ij) {
    int t = blockIdx.x * 256 + threadIdx.x;
    if (t >= C_ * J_) return;
    int c = t % C_;
    int j = t / C_;
    float acc = 0.0f;
    #pragma unroll
    for (int s = 0; s < S_; s++) {
        #pragma unroll
        for (int i = 0; i < I_; i++) {
            acc += W[(((size_t)c * J_ + j) * S_ + s) * I_ + i] *
                   Tb[(size_t)(j * S_ + s) * K1 + i * C_ + c];
        }
    }
    b_ij[c * J_ + j] += acc * (1.0f / (float)B_);
}

// ---------------------------------------------------------------------------
extern "C" void kernel_launch(void* const* d_in, const int* in_sizes, int n_in,
                              void* d_out, int out_size, void* d_ws, size_t ws_size,
                              hipStream_t stream) {
    const float* x = (const float*)d_in[0];   // [512][8][1152]
    const float* W = (const float*)d_in[1];   // [1152][10][16][8]
    float* out = (float*)d_out;               // [512][10][16][1]
    float* ws  = (float*)d_ws;

    float* xT    = ws;                 // 4,718,592
    float* cnorm = xT + 4718592;       // 11,520
    float* Af    = cnorm + 11520;      // 1,474,560
    float* s_buf = Af + 1474560;       // 81,920
    float* vT    = s_buf + 81920;      // 81,920
    float* Tb    = vT + 81920;         // 1,474,560
    float* b_ij  = Tb + 1474560;       // 11,520
    // total: 7,854,592 floats = 31.4 MB

    k_transpose<<<dim3(K1 / 32, B_ / 32), dim3(32, 8), 0, stream>>>(x, xT);
    k_zero<<<45, 256, 0, stream>>>(b_ij, C_ * J_);

    for (int it = 0; it < 3; it++) {
        k_softmax<<<5, 256, 0, stream>>>(b_ij, cnorm);
        k_fold<<<5760, 256, 0, stream>>>(W, cnorm, Af);
        k_zero<<<320, 256, 0, stream>>>(s_buf, J_ * B_ * S_);
        k_sgemm<<<dim3(4, 10, 8), 256, 0, stream>>>(Af, xT, s_buf);
        k_squash<<<20, 256, 0, stream>>>(s_buf, vT, out);
        if (it < 2) {
            k_tgemm<<<dim3(72, 10), 256, 0, stream>>>(vT, x, Tb);
            k_bupdate<<<45, 256, 0, stream>>>(W, Tb, b_ij);
        }
    }
}

// Round 2
// 270.406 us; speedup vs baseline: 1.5662x; 1.5662x over previous
//
#include <hip/hip_runtime.h>
#include <math.h>

#define B_  512
#define I_  8
#define C_  1152
#define J_  10
#define S_  16
#define K1  (I_ * C_)   // 9216
#define NKB (K1 / 32)   // 288 k-blocks for sgemm
#define NTS (B_ / 16)   // 32 n-tiles (sgemm, over b)
#define NTT (K1 / 16)   // 576 n-tiles (tgemm, over i*1152+c)
#define KBT (B_ / 32)   // 16 k-blocks for tgemm

typedef short short8 __attribute__((ext_vector_type(8)));   // 8 bf16 in 4 VGPRs
typedef float floatx4 __attribute__((ext_vector_type(4)));

__device__ inline unsigned short f2bf(float f) {
    unsigned int u = __float_as_uint(f);
    return (unsigned short)((u + 0x7FFFu + ((u >> 16) & 1u)) >> 16);
}
__device__ inline unsigned int pack2(float a, float b) {
    return (unsigned int)f2bf(a) | ((unsigned int)f2bf(b) << 16);
}

// ---------------------------------------------------------------------------
// sgemm B-operand fragments from x:  Bs[((nt*288+kb)*64+L)*8+e] =
//   bf16( x[b=nt*16+(L&15)][k=kb*32+(L>>4)*8+e] )
__global__ __launch_bounds__(256) void k_bfrag_s(const float* __restrict__ x,
                                                 uint4* __restrict__ Bs) {
    int t = blockIdx.x * 256 + threadIdx.x;      // 32*288*64 = 589824
    int L  = t & 63;
    int kb = (t >> 6) % NKB;
    int nt = t / (NKB * 64);
    int b  = nt * 16 + (L & 15);
    int kk = kb * 32 + ((L >> 4) << 3);
    const float* p = x + (size_t)b * K1 + kk;    // 8 consecutive floats
    float4 lo = *(const float4*)p;
    float4 hi = *(const float4*)(p + 4);
    uint4 o;
    o.x = pack2(lo.x, lo.y); o.y = pack2(lo.z, lo.w);
    o.z = pack2(hi.x, hi.y); o.w = pack2(hi.z, hi.w);
    Bs[t] = o;
}

// ---------------------------------------------------------------------------
// tgemm B-operand fragments from x:  Bt[((nt*16+kb)*64+L)*8+e] =
//   bf16( x[b=kb*32+(L>>4)*8+e][n=nt*16+(L&15)] )
__global__ __launch_bounds__(256) void k_bfrag_t(const float* __restrict__ x,
                                                 uint4* __restrict__ Bt) {
    int t = blockIdx.x * 256 + threadIdx.x;      // 576*16*64 = 589824
    int L  = t & 63;
    int kb = (t >> 6) & (KBT - 1);
    int nt = t / (KBT * 64);
    int n  = nt * 16 + (L & 15);
    int bb = kb * 32 + ((L >> 4) << 3);
    float v[8];
    #pragma unroll
    for (int e = 0; e < 8; e++) v[e] = x[(size_t)(bb + e) * K1 + n];
    uint4 o;
    o.x = pack2(v[0], v[1]); o.y = pack2(v[2], v[3]);
    o.z = pack2(v[4], v[5]); o.w = pack2(v[6], v[7]);
    Bt[t] = o;
}

// ---------------------------------------------------------------------------
__global__ __launch_bounds__(256) void k_zero(float* __restrict__ p, int n) {
    int t = blockIdx.x * 256 + threadIdx.x;
    if (t < n) p[t] = 0.0f;
}

// ---------------------------------------------------------------------------
__global__ __launch_bounds__(256) void k_softmax(const float* __restrict__ b_ij,
                                                 float* __restrict__ cnorm) {
    int c = blockIdx.x * 256 + threadIdx.x;
    if (c >= C_) return;
    float v[J_];
    float mx = -1e30f;
    #pragma unroll
    for (int j = 0; j < J_; j++) { v[j] = b_ij[c * J_ + j]; mx = fmaxf(mx, v[j]); }
    float sum = 0.0f;
    #pragma unroll
    for (int j = 0; j < J_; j++) { v[j] = expf(v[j] - mx); sum += v[j]; }
    float inv = 1.0f / sum;
    #pragma unroll
    for (int j = 0; j < J_; j++) cnorm[c * J_ + j] = v[j] * inv;
}

// ---------------------------------------------------------------------------
// A-operand fragments: Af[((j*288+kb)*64+L)*8+e] =
//   bf16( cnorm[c][j] * W[c][j][s=L&15][i] ), k=(i*1152+c)=kb*32+(L>>4)*8+e
__global__ __launch_bounds__(256) void k_fold(const float* __restrict__ W,
                                              const float* __restrict__ cnorm,
                                              uint4* __restrict__ Af) {
    int t = blockIdx.x * 256 + threadIdx.x;      // 10*288*64 = 184320
    int L  = t & 63;
    int kb = (t >> 6) % NKB;
    int j  = t / (NKB * 64);
    int m  = L & 15;
    int kk = kb * 32 + ((L >> 4) << 3);
    int i  = kk / C_;
    int c0 = kk % C_;                            // no i-boundary wrap within 8
    float v[8];
    #pragma unroll
    for (int e = 0; e < 8; e++) {
        v[e] = W[(size_t)(c0 + e) * (J_ * S_ * I_) + j * (S_ * I_) + m * I_ + i] *
               cnorm[(c0 + e) * J_ + j];
    }
    uint4 o;
    o.x = pack2(v[0], v[1]); o.y = pack2(v[2], v[3]);
    o.z = pack2(v[4], v[5]); o.w = pack2(v[6], v[7]);
    Af[t] = o;
}

// ---------------------------------------------------------------------------
// s[j][b][s'] = sum_k Af_j[k][s'] * x[b][k]  via MFMA 16x16x32 bf16
// grid(16 ngroups, 5 j-pairs, 8 kz), 4 waves = 4 k-subsplits, atomicAdd out
__global__ __launch_bounds__(256) void k_sgemm_mfma(const short8* __restrict__ Af,
                                                    const short8* __restrict__ Bs,
                                                    float* __restrict__ s_buf) {
    int t = threadIdx.x, w = t >> 6, L = t & 63;
    int j0  = blockIdx.y * 2;
    int nt0 = blockIdx.x * 2;
    int kb0 = (blockIdx.z * 4 + w) * 9;          // 32 splits * 9 kb = 288
    const short8* pA0 = Af + ((size_t)j0 * NKB + kb0) * 64 + L;
    const short8* pA1 = pA0 + (size_t)NKB * 64;
    const short8* pB0 = Bs + ((size_t)nt0 * NKB + kb0) * 64 + L;
    const short8* pB1 = pB0 + (size_t)NKB * 64;
    floatx4 a00 = {0.f,0.f,0.f,0.f}, a01 = a00, a10 = a00, a11 = a00;
    #pragma unroll
    for (int i = 0; i < 9; i++) {
        short8 fa0 = pA0[i * 64];
        short8 fa1 = pA1[i * 64];
        short8 fb0 = pB0[i * 64];
        short8 fb1 = pB1[i * 64];
        a00 = __builtin_amdgcn_mfma_f32_16x16x32_bf16(fa0, fb0, a00, 0, 0, 0);
        a01 = __builtin_amdgcn_mfma_f32_16x16x32_bf16(fa0, fb1, a01, 0, 0, 0);
        a10 = __builtin_amdgcn_mfma_f32_16x16x32_bf16(fa1, fb0, a10, 0, 0, 0);
        a11 = __builtin_amdgcn_mfma_f32_16x16x32_bf16(fa1, fb1, a11, 0, 0, 0);
    }
    // C/D layout: col = L&15, row = (L>>4)*4 + r
    int col = L & 15, rw = (L >> 4) * 4;
    #pragma unroll
    for (int r = 0; r < 4; r++) {
        atomicAdd(&s_buf[((size_t)j0 * B_ + nt0 * 16 + col) * S_ + rw + r], a00[r]);
        atomicAdd(&s_buf[((size_t)j0 * B_ + (nt0 + 1) * 16 + col) * S_ + rw + r], a01[r]);
        atomicAdd(&s_buf[((size_t)(j0 + 1) * B_ + nt0 * 16 + col) * S_ + rw + r], a10[r]);
        atomicAdd(&s_buf[((size_t)(j0 + 1) * B_ + (nt0 + 1) * 16 + col) * S_ + rw + r], a11[r]);
    }
}

// ---------------------------------------------------------------------------
// squash per (j,b); write out[b][j][s] fp32 and Vf bf16 in A-fragment layout:
//   Vf[((j*16 + (b>>5))*64 + (s | (((b>>3)&3)<<4)))*8 + (b&7)]
__global__ __launch_bounds__(256) void k_squash(const float* __restrict__ s_buf,
                                                unsigned short* __restrict__ Vf,
                                                float* __restrict__ out) {
    int t = blockIdx.x * 256 + threadIdx.x;
    if (t >= J_ * B_) return;
    int j = t / B_;
    int b = t % B_;
    const float* sp = s_buf + ((size_t)j * B_ + b) * S_;
    float sv[S_];
    float msq = 0.0f;
    #pragma unroll
    for (int e = 0; e < S_; e++) { sv[e] = sp[e]; msq += sv[e] * sv[e]; }
    float scale = msq / ((1.0f + msq) * sqrtf(msq));
    int kb = b >> 5, lh = (b >> 3) & 3, e = b & 7;
    #pragma unroll
    for (int s = 0; s < S_; s++) {
        float v = sv[s] * scale;
        out[((size_t)b * J_ + j) * S_ + s] = v;
        Vf[((size_t)(j * 16 + kb) * 64 + (s | (lh << 4))) * 8 + e] = f2bf(v);
    }
}

// ---------------------------------------------------------------------------
// T[m=(j*16+s)][n=(i*1152+c)] = sum_b v[j][b][s] * x[b][n]  via MFMA
// grid(72, 10), 4 waves each take 2 n-tiles; K=512 (16 kb), direct store
__global__ __launch_bounds__(256) void k_tgemm_mfma(const short8* __restrict__ Vf,
                                                    const short8* __restrict__ Bt,
                                                    float* __restrict__ Tb) {
    int t = threadIdx.x, w = t >> 6, L = t & 63;
    int j   = blockIdx.y;
    int nt0 = blockIdx.x * 8 + w * 2;
    const short8* pA  = Vf + (size_t)j * KBT * 64 + L;
    const short8* pB0 = Bt + (size_t)nt0 * KBT * 64 + L;
    const short8* pB1 = pB0 + (size_t)KBT * 64;
    floatx4 a0 = {0.f,0.f,0.f,0.f}, a1 = a0;
    #pragma unroll
    for (int kb = 0; kb < KBT; kb++) {
        short8 fa = pA[kb * 64];
        short8 f0 = pB0[kb * 64];
        short8 f1 = pB1[kb * 64];
        a0 = __builtin_amdgcn_mfma_f32_16x16x32_bf16(fa, f0, a0, 0, 0, 0);
        a1 = __builtin_amdgcn_mfma_f32_16x16x32_bf16(fa, f1, a1, 0, 0, 0);
    }
    int col = L & 15, rw = (L >> 4) * 4;
    #pragma unroll
    for (int r = 0; r < 4; r++) {
        Tb[((size_t)j * 16 + rw + r) * K1 + nt0 * 16 + col] = a0[r];
        Tb[((size_t)j * 16 + rw + r) * K1 + (nt0 + 1) * 16 + col] = a1[r];
    }
}

// ---------------------------------------------------------------------------
// b_ij[c][j] += (1/B) * sum_{s,i} W[c][j][s][i] * T[(j*16+s)][i*1152+c]
__global__ __launch_bounds__(256) void k_bupdate(const float* __restrict__ W,
                                                 const float* __restrict__ Tb,
                                                 float* __restrict__ b_ij) {
    int t = blockIdx.x * 256 + threadIdx.x;
    if (t >= C_ * J_) return;
    int c = t % C_;
    int j = t / C_;
    float acc = 0.0f;
    #pragma unroll
    for (int s = 0; s < S_; s++) {
        #pragma unroll
        for (int i = 0; i < I_; i++) {
            acc += W[(((size_t)c * J_ + j) * S_ + s) * I_ + i] *
                   Tb[(size_t)(j * S_ + s) * K1 + i * C_ + c];
        }
    }
    b_ij[c * J_ + j] += acc * (1.0f / (float)B_);
}

// ---------------------------------------------------------------------------
extern "C" void kernel_launch(void* const* d_in, const int* in_sizes, int n_in,
                              void* d_out, int out_size, void* d_ws, size_t ws_size,
                              hipStream_t stream) {
    const float* x = (const float*)d_in[0];   // [512][8][1152]
    const float* W = (const float*)d_in[1];   // [1152][10][16][8]
    float* out = (float*)d_out;               // [512][10][16][1]
    float* ws  = (float*)d_ws;

    // layout in floats (all 16B-aligned offsets)
    float* Af_f   = ws;                       //   737,280 f (1,474,560 bf16)
    float* Bs_f   = Af_f + 737280;            // 2,359,296 f (4,718,592 bf16)
    float* Bt_f   = Bs_f + 2359296;           // 2,359,296 f
    float* Vf_f   = Bt_f + 2359296;           //    40,960 f (81,920 bf16)
    float* s_buf  = Vf_f + 40960;             //    81,920 f
    float* Tb     = s_buf + 81920;            // 1,474,560 f
    float* cnorm  = Tb + 1474560;             //    11,520 f
    float* b_ij   = cnorm + 11520;            //    11,520 f
    // total 7,076,352 floats = 28.3 MB

    k_bfrag_s<<<2304, 256, 0, stream>>>(x, (uint4*)Bs_f);
    k_bfrag_t<<<2304, 256, 0, stream>>>(x, (uint4*)Bt_f);
    k_zero<<<45, 256, 0, stream>>>(b_ij, C_ * J_);

    for (int it = 0; it < 3; it++) {
        k_softmax<<<5, 256, 0, stream>>>(b_ij, cnorm);
        k_fold<<<720, 256, 0, stream>>>(W, cnorm, (uint4*)Af_f);
        k_zero<<<320, 256, 0, stream>>>(s_buf, J_ * B_ * S_);
        k_sgemm_mfma<<<dim3(16, 5, 8), 256, 0, stream>>>(
            (const short8*)Af_f, (const short8*)Bs_f, s_buf);
        k_squash<<<20, 256, 0, stream>>>(s_buf, (unsigned short*)Vf_f, out);
        if (it < 2) {
            k_tgemm_mfma<<<dim3(72, 10), 256, 0, stream>>>(
                (const short8*)Vf_f, (const short8*)Bt_f, Tb);
            k_bupdate<<<45, 256, 0, stream>>>(W, Tb, b_ij);
        }
    }
}

// Round 3
// 171.727 us; speedup vs baseline: 2.4663x; 1.5746x over previous
//
#include <hip/hip_runtime.h>
#include <math.h>

#define B_  512
#define I_  8
#define C_  1152
#define J_  10
#define S_  16
#define K1  (I_ * C_)   // 9216
#define NKB (K1 / 32)   // 288 k-blocks (sgemm K)
#define KBT (B_ / 32)   // 16 k-blocks (tgemm K)
#define NP  8           // sgemm K-partials

typedef short short8 __attribute__((ext_vector_type(8)));   // 8 bf16
typedef float floatx4 __attribute__((ext_vector_type(4)));

__device__ inline unsigned short f2bf(float f) {
    unsigned int u = __float_as_uint(f);
    return (unsigned short)((u + 0x7FFFu + ((u >> 16) & 1u)) >> 16);
}
__device__ inline unsigned int pack2(float a, float b) {
    return (unsigned int)f2bf(a) | ((unsigned int)f2bf(b) << 16);
}
__device__ inline float bf2f(unsigned short h) {
    return __uint_as_float((unsigned int)h << 16);
}

// ---------------------------------------------------------------------------
// One packing kernel, sections by blockIdx.x:
//  A [0,1152)    : Bs  — x -> sgemm B-fragments (LDS-staged, coalesced)
//  B [1152,2304) : Bt  — x^T -> tgemm B-fragments (LDS-staged transpose)
//  C [2304,3024) : Wf  — W -> A-fragment layout (no cnorm), packed once
//  E [3024,3384) : W2  — W -> [j][i][c][s] bf16 for fused bupdate
//  D [3384,3429) : zero b_ij
__global__ __launch_bounds__(256) void k_pack(const float* __restrict__ x,
                                              const float* __restrict__ W,
                                              uint4* __restrict__ Bs,
                                              uint4* __restrict__ Bt,
                                              uint4* __restrict__ Wf,
                                              unsigned short* __restrict__ W2,
                                              float* __restrict__ b_ij) {
    __shared__ float lds[4288];   // 17152 B: A uses 16x268, B uses 32x132
    const int bu = blockIdx.x;
    const int t  = threadIdx.x;

    if (bu < 1152) {              // ---- Section A: Bs
        int bid = bu;
        int nt = bid / 36, kbg = bid % 36;
        int b0 = nt * 16, k0 = kbg * 256;
        #pragma unroll
        for (int p = 0; p < 4; p++) {
            int idx = p * 256 + t;
            int row = idx >> 6, c4 = (idx & 63) * 4;
            *(float4*)&lds[row * 268 + c4] =
                *(const float4*)&x[(size_t)(b0 + row) * K1 + k0 + c4];
        }
        __syncthreads();
        #pragma unroll
        for (int p = 0; p < 2; p++) {
            int f = p * 256 + t;
            int L = f & 63, q = f >> 6;          // q 0..7
            int row = L & 15;
            int col = q * 32 + ((L >> 4) << 3);
            const float* s = &lds[row * 268 + col];
            uint4 o;
            o.x = pack2(s[0], s[1]); o.y = pack2(s[2], s[3]);
            o.z = pack2(s[4], s[5]); o.w = pack2(s[6], s[7]);
            Bs[((size_t)nt * NKB + kbg * 8 + q) * 64 + L] = o;
        }
    } else if (bu < 2304) {       // ---- Section B: Bt
        int bid = bu - 1152;
        int kb = bid & 15, ntg = bid >> 4;       // ntg 0..71
        int b0 = kb * 32, n0 = ntg * 128;
        #pragma unroll
        for (int p = 0; p < 4; p++) {
            int idx = p * 256 + t;
            int row = idx >> 5, c4 = (idx & 31) * 4;
            *(float4*)&lds[row * 132 + c4] =
                *(const float4*)&x[(size_t)(b0 + row) * K1 + n0 + c4];
        }
        __syncthreads();
        #pragma unroll
        for (int p = 0; p < 2; p++) {
            int f = p * 256 + t;
            int L = f & 63, ntl = f >> 6;        // ntl 0..7
            int bb = (L >> 4) << 3;
            int nl = ntl * 16 + (L & 15);
            float v[8];
            #pragma unroll
            for (int e = 0; e < 8; e++) v[e] = lds[(bb + e) * 132 + nl];
            uint4 o;
            o.x = pack2(v[0], v[1]); o.y = pack2(v[2], v[3]);
            o.z = pack2(v[4], v[5]); o.w = pack2(v[6], v[7]);
            Bt[((size_t)(ntg * 8 + ntl) * KBT + kb) * 64 + L] = o;
        }
    } else if (bu < 3024) {       // ---- Section C: Wf
        int tg = (bu - 2304) * 256 + t;          // 0..184319
        int L  = tg & 63;
        int kb = (tg >> 6) % NKB;
        int j  = tg / (NKB * 64);
        int m  = L & 15;
        int kk = kb * 32 + ((L >> 4) << 3);
        int i  = kk / C_, c0 = kk % C_;
        float v[8];
        #pragma unroll
        for (int e = 0; e < 8; e++)
            v[e] = W[(size_t)(c0 + e) * 1280 + j * 128 + m * 8 + i];
        uint4 o;
        o.x = pack2(v[0], v[1]); o.y = pack2(v[2], v[3]);
        o.z = pack2(v[4], v[5]); o.w = pack2(v[6], v[7]);
        Wf[tg] = o;
    } else if (bu < 3384) {       // ---- Section E: W2[j][i][c][s]
        int tg = (bu - 3024) * 256 + t;          // 0..92159 triples
        int c = tg % C_;
        int i = (tg / C_) & 7;
        int j = tg / (C_ * I_);
        unsigned short o[16];
        #pragma unroll
        for (int s = 0; s < S_; s++)
            o[s] = f2bf(W[(size_t)(c * J_ + j) * 128 + s * 8 + i]);
        *(uint4*)&W2[(size_t)tg * 16]     = *(uint4*)&o[0];
        *(uint4*)&W2[(size_t)tg * 16 + 8] = *(uint4*)&o[8];
    } else {                      // ---- Section D: zero b_ij
        int idx = (bu - 3384) * 256 + t;
        if (idx < C_ * J_) b_ij[idx] = 0.0f;
    }
}

// ---------------------------------------------------------------------------
// Per-iteration: inline softmax (cooperative, 128 c per block) + Af = Wf * cn
__global__ __launch_bounds__(256) void k_fold2(const uint4* __restrict__ Wf,
                                               const float* __restrict__ b_ij,
                                               uint4* __restrict__ Af) {
    __shared__ float cnL[128];
    const int blk = blockIdx.x;                  // 720
    const int t   = threadIdx.x;
    const int j   = blk / 72;
    const int r   = blk % 72;
    const int kb0 = r * 4;
    const int c0  = (kb0 * 32) % C_;             // 128 | 1152 -> exact
    if (t < 128) {
        int c = c0 + t;
        float bv[J_], mx = -1e30f;
        #pragma unroll
        for (int jj = 0; jj < J_; jj++) { bv[jj] = b_ij[c * J_ + jj]; mx = fmaxf(mx, bv[jj]); }
        float sum = 0.0f;
        #pragma unroll
        for (int jj = 0; jj < J_; jj++) sum += expf(bv[jj] - mx);
        cnL[t] = expf(bv[j] - mx) / sum;
    }
    __syncthreads();
    int L = t & 63;
    size_t flat = ((size_t)j * NKB + kb0 + (t >> 6)) * 64 + L;
    int off = (t >> 6) * 32 + ((L >> 4) << 3);
    uint4 wv = Wf[flat];
    unsigned int u[4] = {wv.x, wv.y, wv.z, wv.w};
    uint4 o;
    unsigned int* po = (unsigned int*)&o;
    #pragma unroll
    for (int h = 0; h < 4; h++) {
        float f0 = __uint_as_float(u[h] << 16) * cnL[off + 2 * h];
        float f1 = __uint_as_float(u[h] & 0xffff0000u) * cnL[off + 2 * h + 1];
        po[h] = pack2(f0, f1);
    }
    Af[flat] = o;
}

// ---------------------------------------------------------------------------
// s-partials: grid(32 nt, 5 jp, 2 kz), each wave = one K-split p = bz*4+w.
// part[p][j][b][s] written non-atomically, fully coalesced.
__global__ __launch_bounds__(256) void k_sgemm(const short8* __restrict__ Af,
                                               const short8* __restrict__ Bs,
                                               float* __restrict__ part) {
    const int t = threadIdx.x, w = t >> 6, L = t & 63;
    const int nt = blockIdx.x;
    const int j0 = blockIdx.y * 2;
    const int p  = blockIdx.z * 4 + w;           // 0..7
    const int kb0 = p * 36;                      // 8 * 36 = 288
    const short8* pA0 = Af + ((size_t)j0 * NKB + kb0) * 64 + L;
    const short8* pA1 = pA0 + (size_t)NKB * 64;
    const short8* pB  = Bs + ((size_t)nt * NKB + kb0) * 64 + L;
    floatx4 a0 = {0.f, 0.f, 0.f, 0.f}, a1 = a0;
    #pragma unroll 6
    for (int i = 0; i < 36; i++) {
        short8 fb = pB[i * 64];
        a0 = __builtin_amdgcn_mfma_f32_16x16x32_bf16(pA0[i * 64], fb, a0, 0, 0, 0);
        a1 = __builtin_amdgcn_mfma_f32_16x16x32_bf16(pA1[i * 64], fb, a1, 0, 0, 0);
    }
    int col = L & 15, rw = (L >> 4) * 4;
    int b = nt * 16 + col;
    *(floatx4*)&part[(((size_t)p * J_ + j0) * B_ + b) * S_ + rw] = a0;
    *(floatx4*)&part[(((size_t)p * J_ + j0 + 1) * B_ + b) * S_ + rw] = a1;
}

// ---------------------------------------------------------------------------
// Reduce 8 partials + squash; write out (fp32) and Vf (bf16 A-fragments)
__global__ __launch_bounds__(256) void k_redsq(const float* __restrict__ part,
                                               unsigned short* __restrict__ Vf,
                                               float* __restrict__ out) {
    int tg = blockIdx.x * 256 + threadIdx.x;     // 0..5119
    if (tg >= J_ * B_) return;
    int j = tg / B_;
    int b = tg % B_;
    floatx4 sv4[4];
    #pragma unroll
    for (int r4 = 0; r4 < 4; r4++) {
        floatx4 acc = {0.f, 0.f, 0.f, 0.f};
        #pragma unroll
        for (int p = 0; p < NP; p++)
            acc += *(const floatx4*)&part[(((size_t)p * J_ + j) * B_ + b) * S_ + r4 * 4];
        sv4[r4] = acc;
    }
    const float* sv = (const float*)sv4;
    float msq = 0.0f;
    #pragma unroll
    for (int e = 0; e < S_; e++) msq += sv[e] * sv[e];
    float scale = msq / ((1.0f + msq) * sqrtf(msq));
    int kb = b >> 5, lh = (b >> 3) & 3, e = b & 7;
    #pragma unroll
    for (int s = 0; s < S_; s++) {
        float v = sv[s] * scale;
        out[((size_t)b * J_ + j) * S_ + s] = v;
        Vf[((size_t)(j * KBT + kb) * 64 + (s | (lh << 4))) * 8 + e] = f2bf(v);
    }
}

// ---------------------------------------------------------------------------
// T-tile via MFMA, then fused b_ij update through LDS (no Tb round-trip).
// grid(72 ntg, 10 j); block owns n0=bx*128 -> single i, contiguous 128 c.
__global__ __launch_bounds__(256) void k_tgemm_bup(const short8* __restrict__ Vf,
                                                   const short8* __restrict__ Bt,
                                                   const unsigned short* __restrict__ W2,
                                                   float* __restrict__ b_ij) {
    __shared__ float Tl[16 * 132];
    const int t = threadIdx.x, w = t >> 6, L = t & 63;
    const int j  = blockIdx.y;
    const int n0 = blockIdx.x * 128;
    const int i  = n0 / C_, c0 = n0 % C_;
    const int nt0 = blockIdx.x * 8 + w * 2;
    const short8* pA  = Vf + (size_t)j * KBT * 64 + L;
    const short8* pB0 = Bt + (size_t)nt0 * KBT * 64 + L;
    const short8* pB1 = pB0 + (size_t)KBT * 64;
    floatx4 a0 = {0.f, 0.f, 0.f, 0.f}, a1 = a0;
    #pragma unroll
    for (int kb = 0; kb < KBT; kb++) {
        short8 fa = pA[kb * 64];
        a0 = __builtin_amdgcn_mfma_f32_16x16x32_bf16(fa, pB0[kb * 64], a0, 0, 0, 0);
        a1 = __builtin_amdgcn_mfma_f32_16x16x32_bf16(fa, pB1[kb * 64], a1, 0, 0, 0);
    }
    int col = L & 15, rw = (L >> 4) * 4;
    int nl0 = w * 32 + col;
    #pragma unroll
    for (int r = 0; r < 4; r++) {
        Tl[(rw + r) * 132 + nl0]      = a0[r];
        Tl[(rw + r) * 132 + nl0 + 16] = a1[r];
    }
    __syncthreads();
    if (t < 128) {
        int c = c0 + t;
        const unsigned short* wp = W2 + ((size_t)(j * I_ + i) * C_ + c) * 16;
        uint4 w0 = *(const uint4*)wp;
        uint4 w1 = *(const uint4*)(wp + 8);
        unsigned int uw[8] = {w0.x, w0.y, w0.z, w0.w, w1.x, w1.y, w1.z, w1.w};
        float sum = 0.0f;
        #pragma unroll
        for (int h = 0; h < 8; h++) {
            sum += Tl[(2 * h) * 132 + t]     * __uint_as_float(uw[h] << 16);
            sum += Tl[(2 * h + 1) * 132 + t] * __uint_as_float(uw[h] & 0xffff0000u);
        }
        atomicAdd(&b_ij[c * J_ + j], sum * (1.0f / (float)B_));
    }
}

// ---------------------------------------------------------------------------
extern "C" void kernel_launch(void* const* d_in, const int* in_sizes, int n_in,
                              void* d_out, int out_size, void* d_ws, size_t ws_size,
                              hipStream_t stream) {
    const float* x = (const float*)d_in[0];   // [512][8][1152]
    const float* W = (const float*)d_in[1];   // [1152][10][16][8]
    float* out = (float*)d_out;               // [512][10][16][1]
    float* ws  = (float*)d_ws;

    // workspace layout (floats, all 16B-aligned)
    float* Wf_f  = ws;                   //   737,280 f (1,474,560 bf16)
    float* Af_f  = Wf_f + 737280;        //   737,280 f
    float* Bs_f  = Af_f + 737280;        // 2,359,296 f
    float* Bt_f  = Bs_f + 2359296;       // 2,359,296 f
    float* W2_f  = Bt_f + 2359296;       //   737,280 f (1,474,560 bf16)
    float* Vf_f  = W2_f + 737280;        //    40,960 f
    float* part  = Vf_f + 40960;         //   655,360 f  [8][10][512][16]
    float* b_ij  = part + 655360;        //    11,520 f
    // total 7,637,272 floats ~= 30.5 MB

    k_pack<<<3429, 256, 0, stream>>>(x, W, (uint4*)Bs_f, (uint4*)Bt_f,
                                     (uint4*)Wf_f, (unsigned short*)W2_f, b_ij);

    for (int it = 0; it < 3; it++) {
        k_fold2<<<720, 256, 0, stream>>>((const uint4*)Wf_f, b_ij, (uint4*)Af_f);
        k_sgemm<<<dim3(32, 5, 2), 256, 0, stream>>>(
            (const short8*)Af_f, (const short8*)Bs_f, part);
        k_redsq<<<20, 256, 0, stream>>>(part, (unsigned short*)Vf_f, out);
        if (it < 2) {
            k_tgemm_bup<<<dim3(72, 10), 256, 0, stream>>>(
                (const short8*)Vf_f, (const short8*)Bt_f,
                (const unsigned short*)W2_f, b_ij);
        }
    }
}